// Round 1
// baseline (3275.679 us; speedup 1.0000x reference)
//
#include <hip/hip_runtime.h>
#include <hip/hip_bf16.h>

#define HD 128
#define LN_EPS 1e-5f

__device__ __forceinline__ float wave_sum(float v) {
    #pragma unroll
    for (int o = 32; o > 0; o >>= 1) v += __shfl_down(v, o);
    return v;
}

// h = relu(LN(x @ W + b))   x:(N,256) W:(256,128)
__global__ __launch_bounds__(256) void proj_ln_kernel(
    const float* __restrict__ x, const float* __restrict__ W,
    const float* __restrict__ bias, const float* __restrict__ g,
    const float* __restrict__ be, float* __restrict__ h, int N)
{
    __shared__ __align__(16) float w[256 * HD];     // 128 KB
    __shared__ __align__(16) float xs[2][256];
    __shared__ float red[2][2][2];
    for (int i = threadIdx.x; i < 256 * HD; i += 256) w[i] = W[i];
    int sub = threadIdx.x >> 7, t = threadIdx.x & 127;
    float bj = bias[t], gj = g[t], bej = be[t];
    __syncthreads();
    for (int base = blockIdx.x * 2; base < N; base += gridDim.x * 2) {
        int i = base + sub; bool val = i < N;
        if (val) { xs[sub][t] = x[(size_t)i * 256 + t]; xs[sub][128 + t] = x[(size_t)i * 256 + 128 + t]; }
        __syncthreads();
        float acc = bj;
        const float* xr = xs[sub];
        #pragma unroll 8
        for (int k = 0; k < 256; k += 4) {
            float4 xv = *(const float4*)(xr + k);
            acc = fmaf(xv.x, w[(k + 0) * HD + t], acc);
            acc = fmaf(xv.y, w[(k + 1) * HD + t], acc);
            acc = fmaf(xv.z, w[(k + 2) * HD + t], acc);
            acc = fmaf(xv.w, w[(k + 3) * HD + t], acc);
        }
        float s = wave_sum(acc), s2 = wave_sum(acc * acc);
        int lane = threadIdx.x & 63;
        if (lane == 0) { red[sub][0][t >> 6] = s; red[sub][1][t >> 6] = s2; }
        __syncthreads();
        float mu  = (red[sub][0][0] + red[sub][0][1]) * (1.f / 128.f);
        float var = (red[sub][1][0] + red[sub][1][1]) * (1.f / 128.f) - mu * mu;
        float y = (acc - mu) * rsqrtf(var + LN_EPS) * gj + bej;
        if (val) h[(size_t)i * HD + t] = fmaxf(y, 0.f);
        __syncthreads();
    }
}

// out = hin @ W (+bias)    W:(128,128) row-major
__global__ __launch_bounds__(256) void nodegemm_kernel(
    const float* __restrict__ hin, const float* __restrict__ W,
    const float* __restrict__ bias, float* __restrict__ out, int N)
{
    __shared__ __align__(16) float w[HD * HD];      // 64 KB
    __shared__ __align__(16) float xs[2][HD];
    for (int i = threadIdx.x; i < HD * HD; i += 256) w[i] = W[i];
    int sub = threadIdx.x >> 7, t = threadIdx.x & 127;
    float bj = bias ? bias[t] : 0.f;
    __syncthreads();
    for (int base = blockIdx.x * 2; base < N; base += gridDim.x * 2) {
        int i = base + sub; bool val = i < N;
        if (val) xs[sub][t] = hin[(size_t)i * HD + t];
        __syncthreads();
        float acc = bj;
        const float* xr = xs[sub];
        #pragma unroll 8
        for (int k = 0; k < HD; k += 4) {
            float4 xv = *(const float4*)(xr + k);
            acc = fmaf(xv.x, w[(k + 0) * HD + t], acc);
            acc = fmaf(xv.y, w[(k + 1) * HD + t], acc);
            acc = fmaf(xv.z, w[(k + 2) * HD + t], acc);
            acc = fmaf(xv.w, w[(k + 3) * HD + t], acc);
        }
        if (val) out[(size_t)i * HD + t] = acc;
        __syncthreads();
    }
}

// per edge e: d=|h[dst]-h[src]|; hm=relu(A[dst]+B[src]+d@W1c);
// score=sigmoid(dot(hm,W2)+b2); atomic agg[dst] += score*M[src]
__global__ __launch_bounds__(256) void edge_kernel(
    const float* __restrict__ hin, const float* __restrict__ A,
    const float* __restrict__ B, const float* __restrict__ M,
    const int* __restrict__ srcA, const int* __restrict__ dstA,
    const float* __restrict__ W1c, const float* __restrict__ W2,
    const float* __restrict__ B2, float* __restrict__ agg, int E, int N)
{
    __shared__ __align__(16) float w[HD * HD];      // 64 KB
    __shared__ float w2s[HD];
    __shared__ __align__(16) float ds[2][HD];
    __shared__ float red[2][2];
    for (int i = threadIdx.x; i < HD * HD; i += 256) w[i] = W1c[i];
    if (threadIdx.x < HD) w2s[threadIdx.x] = W2[threadIdx.x];
    int sub = threadIdx.x >> 7, t = threadIdx.x & 127;
    float b2 = B2[0];
    __syncthreads();
    int Etot = E + N;
    for (int base = blockIdx.x * 2; base < Etot; base += gridDim.x * 2) {
        int e = base + sub; bool val = e < Etot;
        int si = 0, di = 0; float a = 0.f, m = 0.f, dd = 0.f;
        if (val) {
            si = (e < E) ? srcA[e] : (e - E);
            di = (e < E) ? dstA[e] : (e - E);
            float xi = hin[(size_t)di * HD + t], xj = hin[(size_t)si * HD + t];
            a = A[(size_t)di * HD + t] + B[(size_t)si * HD + t];
            m = M[(size_t)si * HD + t];
            dd = fabsf(xi - xj);
        }
        ds[sub][t] = dd;
        __syncthreads();
        float hm = a;
        const float* dr = ds[sub];
        #pragma unroll 8
        for (int k = 0; k < HD; k += 4) {
            float4 dv = *(const float4*)(dr + k);
            hm = fmaf(dv.x, w[(k + 0) * HD + t], hm);
            hm = fmaf(dv.y, w[(k + 1) * HD + t], hm);
            hm = fmaf(dv.z, w[(k + 2) * HD + t], hm);
            hm = fmaf(dv.w, w[(k + 3) * HD + t], hm);
        }
        hm = fmaxf(hm, 0.f);
        float v = wave_sum(hm * w2s[t]);
        int lane = threadIdx.x & 63;
        if (lane == 0) red[sub][t >> 6] = v;
        __syncthreads();
        float z = red[sub][0] + red[sub][1] + b2;
        float score = 1.f / (1.f + __expf(-z));
        if (val) atomicAdd(&agg[(size_t)di * HD + t], score * m);
        __syncthreads();
    }
}

// h = relu(LN(cat(h,agg)@Wu + bu + h))   Wu:(256,128)
__global__ __launch_bounds__(256) void update_ln_kernel(
    const float* __restrict__ hin, const float* __restrict__ agg,
    const float* __restrict__ W, const float* __restrict__ bias,
    const float* __restrict__ g, const float* __restrict__ be,
    float* __restrict__ hout, int N)
{
    __shared__ __align__(16) float w[256 * HD];     // 128 KB
    __shared__ __align__(16) float cat[2][256];
    __shared__ float red[2][2][2];
    for (int i = threadIdx.x; i < 256 * HD; i += 256) w[i] = W[i];
    int sub = threadIdx.x >> 7, t = threadIdx.x & 127;
    float bj = bias[t], gj = g[t], bej = be[t];
    __syncthreads();
    for (int base = blockIdx.x * 2; base < N; base += gridDim.x * 2) {
        int i = base + sub; bool val = i < N;
        float hv = 0.f;
        if (val) {
            hv = hin[(size_t)i * HD + t];
            cat[sub][t] = hv;
            cat[sub][128 + t] = agg[(size_t)i * HD + t];
        }
        __syncthreads();
        float acc = bj + hv;   // residual
        const float* xr = cat[sub];
        #pragma unroll 8
        for (int k = 0; k < 256; k += 4) {
            float4 xv = *(const float4*)(xr + k);
            acc = fmaf(xv.x, w[(k + 0) * HD + t], acc);
            acc = fmaf(xv.y, w[(k + 1) * HD + t], acc);
            acc = fmaf(xv.z, w[(k + 2) * HD + t], acc);
            acc = fmaf(xv.w, w[(k + 3) * HD + t], acc);
        }
        float s = wave_sum(acc), s2 = wave_sum(acc * acc);
        int lane = threadIdx.x & 63;
        if (lane == 0) { red[sub][0][t >> 6] = s; red[sub][1][t >> 6] = s2; }
        __syncthreads();
        float mu  = (red[sub][0][0] + red[sub][0][1]) * (1.f / 128.f);
        float var = (red[sub][1][0] + red[sub][1][1]) * (1.f / 128.f) - mu * mu;
        float y = (acc - mu) * rsqrtf(var + LN_EPS) * gj + bej;
        if (val) hout[(size_t)i * HD + t] = fmaxf(y, 0.f);
        __syncthreads();
    }
}

// logits = relu(h@W1+b1)@W2+b2   W1:(128,64) W2:(64,40)
__global__ __launch_bounds__(256) void cls_kernel(
    const float* __restrict__ hin, const float* __restrict__ W1,
    const float* __restrict__ b1, const float* __restrict__ W2,
    const float* __restrict__ b2, float* __restrict__ out, int N)
{
    __shared__ __align__(16) float w1[HD * 64];     // 32 KB
    __shared__ __align__(16) float w2[64 * 40];     // 10 KB
    __shared__ __align__(16) float hs[4][HD];
    __shared__ float ts[4][64];
    for (int i = threadIdx.x; i < HD * 64; i += 256) w1[i] = W1[i];
    for (int i = threadIdx.x; i < 64 * 40; i += 256) w2[i] = W2[i];
    int sub = threadIdx.x >> 6, t = threadIdx.x & 63;
    float b1j = b1[t];
    float b2j = (t < 40) ? b2[t] : 0.f;
    __syncthreads();
    for (int base = blockIdx.x * 4; base < N; base += gridDim.x * 4) {
        int i = base + sub; bool val = i < N;
        if (val) { hs[sub][t] = hin[(size_t)i * HD + t]; hs[sub][64 + t] = hin[(size_t)i * HD + 64 + t]; }
        __syncthreads();
        float acc = b1j;
        const float* hr = hs[sub];
        #pragma unroll 8
        for (int k = 0; k < HD; k += 4) {
            float4 hv = *(const float4*)(hr + k);
            acc = fmaf(hv.x, w1[(k + 0) * 64 + t], acc);
            acc = fmaf(hv.y, w1[(k + 1) * 64 + t], acc);
            acc = fmaf(hv.z, w1[(k + 2) * 64 + t], acc);
            acc = fmaf(hv.w, w1[(k + 3) * 64 + t], acc);
        }
        ts[sub][t] = fmaxf(acc, 0.f);
        __syncthreads();
        if (val && t < 40) {
            float o = b2j;
            const float* tr = ts[sub];
            #pragma unroll 8
            for (int k = 0; k < 64; k++) o = fmaf(tr[k], w2[k * 40 + t], o);
            out[(size_t)i * 40 + t] = o;
        }
        __syncthreads();
    }
}

extern "C" void kernel_launch(void* const* d_in, const int* in_sizes, int n_in,
                              void* d_out, int out_size, void* d_ws, size_t ws_size,
                              hipStream_t stream)
{
    const float* x      = (const float*)d_in[0];
    const int*   ei     = (const int*)d_in[1];
    const float* proj_W = (const float*)d_in[2];
    const float* proj_b = (const float*)d_in[3];
    const float* ln0_g  = (const float*)d_in[4];
    const float* ln0_b  = (const float*)d_in[5];
    const float* sim_W1 = (const float*)d_in[6];
    const float* sim_b1 = (const float*)d_in[7];
    const float* sim_W2 = (const float*)d_in[8];
    const float* sim_b2 = (const float*)d_in[9];
    const float* W_msg  = (const float*)d_in[10];
    const float* W_upd  = (const float*)d_in[11];
    const float* b_upd  = (const float*)d_in[12];
    const float* ln_g   = (const float*)d_in[13];
    const float* ln_b   = (const float*)d_in[14];
    const float* cls_W1 = (const float*)d_in[15];
    const float* cls_b1 = (const float*)d_in[16];
    const float* cls_W2 = (const float*)d_in[17];
    const float* cls_b2 = (const float*)d_in[18];

    int N = in_sizes[0] / 256;
    int E = in_sizes[1] / 2;
    int L = in_sizes[6] / (3 * HD * HD);   // = 3
    const int* srcA = ei;
    const int* dstA = ei + E;

    float* ws = (float*)d_ws;
    size_t nh = (size_t)N * HD;
    float* h   = ws;
    float* A   = h + nh;
    float* B   = A + nh;
    float* M   = B + nh;
    float* agg = M + nh;

    proj_ln_kernel<<<256, 256, 0, stream>>>(x, proj_W, proj_b, ln0_g, ln0_b, h, N);
    for (int l = 0; l < L; l++) {
        const float* W1 = sim_W1 + (size_t)l * 3 * HD * HD;
        nodegemm_kernel<<<512, 256, 0, stream>>>(h, W1,                      sim_b1 + l * HD, A, N);
        nodegemm_kernel<<<512, 256, 0, stream>>>(h, W1 + HD * HD,            nullptr,         B, N);
        nodegemm_kernel<<<512, 256, 0, stream>>>(h, W_msg + (size_t)l * HD * HD, nullptr,     M, N);
        hipMemsetAsync(agg, 0, nh * sizeof(float), stream);
        edge_kernel<<<512, 256, 0, stream>>>(h, A, B, M, srcA, dstA,
                                             W1 + 2 * HD * HD, sim_W2 + l * HD, sim_b2 + l,
                                             agg, E, N);
        update_ln_kernel<<<256, 256, 0, stream>>>(h, agg, W_upd + (size_t)l * 2 * HD * HD,
                                                  b_upd + l * HD, ln_g + l * HD, ln_b + l * HD, h, N);
    }
    cls_kernel<<<768, 256, 0, stream>>>(h, cls_W1, cls_b1, cls_W2, cls_b2, (float*)d_out, N);
}

// Round 2
// 2484.021 us; speedup vs baseline: 1.3187x; 1.3187x over previous
//
#include <hip/hip_runtime.h>
#include <hip/hip_bf16.h>

#define HD 128
#define LN_EPS 1e-5f
#define TE 8   // edges (or rows) per wave iteration

__device__ __forceinline__ float wave_sum(float v) {
    #pragma unroll
    for (int o = 32; o > 0; o >>= 1) v += __shfl_down(v, o);
    return v;
}

__device__ __forceinline__ float wave_sum_all(float v) {
    #pragma unroll
    for (int o = 32; o > 0; o >>= 1) v += __shfl_xor(v, o);
    return v;
}

// h = relu(LN(x @ W + b))   x:(N,256) W:(256,128)
__global__ __launch_bounds__(256) void proj_ln_kernel(
    const float* __restrict__ x, const float* __restrict__ W,
    const float* __restrict__ bias, const float* __restrict__ g,
    const float* __restrict__ be, float* __restrict__ h, int N)
{
    __shared__ __align__(16) float w[256 * HD];     // 128 KB
    __shared__ __align__(16) float xs[2][256];
    __shared__ float red[2][2][2];
    for (int i = threadIdx.x; i < 256 * HD; i += 256) w[i] = W[i];
    int sub = threadIdx.x >> 7, t = threadIdx.x & 127;
    float bj = bias[t], gj = g[t], bej = be[t];
    __syncthreads();
    for (int base = blockIdx.x * 2; base < N; base += gridDim.x * 2) {
        int i = base + sub; bool val = i < N;
        if (val) { xs[sub][t] = x[(size_t)i * 256 + t]; xs[sub][128 + t] = x[(size_t)i * 256 + 128 + t]; }
        __syncthreads();
        float acc = bj;
        const float* xr = xs[sub];
        #pragma unroll 8
        for (int k = 0; k < 256; k += 4) {
            float4 xv = *(const float4*)(xr + k);
            acc = fmaf(xv.x, w[(k + 0) * HD + t], acc);
            acc = fmaf(xv.y, w[(k + 1) * HD + t], acc);
            acc = fmaf(xv.z, w[(k + 2) * HD + t], acc);
            acc = fmaf(xv.w, w[(k + 3) * HD + t], acc);
        }
        float s = wave_sum(acc), s2 = wave_sum(acc * acc);
        int lane = threadIdx.x & 63;
        if (lane == 0) { red[sub][0][t >> 6] = s; red[sub][1][t >> 6] = s2; }
        __syncthreads();
        float mu  = (red[sub][0][0] + red[sub][0][1]) * (1.f / 128.f);
        float var = (red[sub][1][0] + red[sub][1][1]) * (1.f / 128.f) - mu * mu;
        float y = (acc - mu) * rsqrtf(var + LN_EPS) * gj + bej;
        if (val) h[(size_t)i * HD + t] = fmaxf(y, 0.f);
        __syncthreads();
    }
}

// out = hin @ W (+bias)    W:(128,128) row-major.  Wave-per-8-rows, barrier-free.
__global__ __launch_bounds__(256) void nodegemm_kernel(
    const float* __restrict__ hin, const float* __restrict__ W,
    const float* __restrict__ bias, float* __restrict__ out, int N)
{
    __shared__ __align__(16) float wsm[HD * HD];      // 64 KB
    __shared__ __align__(16) float dbuf[4][TE][HD];   // 16 KB
    for (int i = threadIdx.x; i < HD * HD; i += 256) wsm[i] = W[i];
    int wave = threadIdx.x >> 6, lane = threadIdx.x & 63;
    __syncthreads();
    float2 bj = make_float2(0.f, 0.f);
    if (bias) bj = ((const float2*)bias)[lane];
    int gw = blockIdx.x * 4 + wave, nw = gridDim.x * 4;
    int ngroups = (N + TE - 1) / TE;
    for (int grp = gw; grp < ngroups; grp += nw) {
        int rbase = grp * TE;
        int cnt = min(TE, N - rbase);
        float2 acc[TE];
        #pragma unroll
        for (int t = 0; t < TE; t++) {
            int r = (t < cnt) ? (rbase + t) : rbase;
            float2 hv = ((const float2*)(hin + (size_t)r * HD))[lane];
            ((float2*)dbuf[wave][t])[lane] = hv;
            acc[t] = bj;
        }
        asm volatile("s_waitcnt lgkmcnt(0)" ::: "memory");
        #pragma unroll 2
        for (int k = 0; k < HD; k += 4) {
            float2 wv0 = *(const float2*)(wsm + (k + 0) * HD + 2 * lane);
            float2 wv1 = *(const float2*)(wsm + (k + 1) * HD + 2 * lane);
            float2 wv2 = *(const float2*)(wsm + (k + 2) * HD + 2 * lane);
            float2 wv3 = *(const float2*)(wsm + (k + 3) * HD + 2 * lane);
            #pragma unroll
            for (int t = 0; t < TE; t++) {
                float4 dv = *(const float4*)(&dbuf[wave][t][k]);
                acc[t].x = fmaf(dv.x, wv0.x, acc[t].x); acc[t].y = fmaf(dv.x, wv0.y, acc[t].y);
                acc[t].x = fmaf(dv.y, wv1.x, acc[t].x); acc[t].y = fmaf(dv.y, wv1.y, acc[t].y);
                acc[t].x = fmaf(dv.z, wv2.x, acc[t].x); acc[t].y = fmaf(dv.z, wv2.y, acc[t].y);
                acc[t].x = fmaf(dv.w, wv3.x, acc[t].x); acc[t].y = fmaf(dv.w, wv3.y, acc[t].y);
            }
        }
        #pragma unroll
        for (int t = 0; t < TE; t++) {
            if (t < cnt)
                ((float2*)(out + (size_t)(rbase + t) * HD))[lane] = acc[t];
        }
    }
}

// per edge e: d=|h[dst]-h[src]|; hm=relu(A[dst]+B[src]+d@W1c);
// score=sigmoid(dot(hm,W2)+b2); atomic agg[dst] += score*M[src]
// Wave-per-8-edges, no block barriers in the main loop.
__global__ __launch_bounds__(256) void edge_kernel(
    const float* __restrict__ hin, const float* __restrict__ A,
    const float* __restrict__ B, const float* __restrict__ M,
    const int* __restrict__ srcA, const int* __restrict__ dstA,
    const float* __restrict__ W1c, const float* __restrict__ W2,
    const float* __restrict__ B2, float* __restrict__ agg, int E, int N)
{
    __shared__ __align__(16) float wsm[HD * HD];      // 64 KB  [k][out]
    __shared__ __align__(16) float dbuf[4][TE][HD];   // 16 KB
    __shared__ float w2s[HD];
    for (int i = threadIdx.x; i < HD * HD; i += 256) wsm[i] = W1c[i];
    if (threadIdx.x < HD) w2s[threadIdx.x] = W2[threadIdx.x];
    int wave = threadIdx.x >> 6, lane = threadIdx.x & 63;
    __syncthreads();
    float2 w2v = ((const float2*)w2s)[lane];
    float b2 = B2[0];
    int gw = blockIdx.x * 4 + wave, nw = gridDim.x * 4;
    int Etot = E + N;
    int ngroups = (Etot + TE - 1) / TE;
    for (int grp = gw; grp < ngroups; grp += nw) {
        int ebase = grp * TE;
        int cnt = min(TE, Etot - ebase);
        float2 acc[TE], mreg[TE];
        int dix[TE];
        #pragma unroll
        for (int t = 0; t < TE; t++) {
            int e = (t < cnt) ? (ebase + t) : ebase;
            int si = (e < E) ? srcA[e] : (e - E);
            int di = (e < E) ? dstA[e] : (e - E);
            dix[t] = di;
            float2 xi = ((const float2*)(hin + (size_t)di * HD))[lane];
            float2 xj = ((const float2*)(hin + (size_t)si * HD))[lane];
            float2 av = ((const float2*)(A + (size_t)di * HD))[lane];
            float2 bv = ((const float2*)(B + (size_t)si * HD))[lane];
            mreg[t]  = ((const float2*)(M + (size_t)si * HD))[lane];
            acc[t] = make_float2(av.x + bv.x, av.y + bv.y);
            float2 dv = make_float2(fabsf(xi.x - xj.x), fabsf(xi.y - xj.y));
            ((float2*)dbuf[wave][t])[lane] = dv;
        }
        asm volatile("s_waitcnt lgkmcnt(0)" ::: "memory");
        #pragma unroll 2
        for (int k = 0; k < HD; k += 4) {
            float2 wv0 = *(const float2*)(wsm + (k + 0) * HD + 2 * lane);
            float2 wv1 = *(const float2*)(wsm + (k + 1) * HD + 2 * lane);
            float2 wv2 = *(const float2*)(wsm + (k + 2) * HD + 2 * lane);
            float2 wv3 = *(const float2*)(wsm + (k + 3) * HD + 2 * lane);
            #pragma unroll
            for (int t = 0; t < TE; t++) {
                float4 dv = *(const float4*)(&dbuf[wave][t][k]);
                acc[t].x = fmaf(dv.x, wv0.x, acc[t].x); acc[t].y = fmaf(dv.x, wv0.y, acc[t].y);
                acc[t].x = fmaf(dv.y, wv1.x, acc[t].x); acc[t].y = fmaf(dv.y, wv1.y, acc[t].y);
                acc[t].x = fmaf(dv.z, wv2.x, acc[t].x); acc[t].y = fmaf(dv.z, wv2.y, acc[t].y);
                acc[t].x = fmaf(dv.w, wv3.x, acc[t].x); acc[t].y = fmaf(dv.w, wv3.y, acc[t].y);
            }
        }
        #pragma unroll
        for (int t = 0; t < TE; t++) {
            float v = fmaxf(acc[t].x, 0.f) * w2v.x + fmaxf(acc[t].y, 0.f) * w2v.y;
            v = wave_sum_all(v);
            float score = 1.f / (1.f + __expf(-(v + b2)));
            if (t < cnt) {
                atomicAdd(&agg[(size_t)dix[t] * HD + 2 * lane],     score * mreg[t].x);
                atomicAdd(&agg[(size_t)dix[t] * HD + 2 * lane + 1], score * mreg[t].y);
            }
        }
    }
}

// h = relu(LN(cat(h,agg)@Wu + bu + h))   Wu:(256,128)
__global__ __launch_bounds__(256) void update_ln_kernel(
    const float* __restrict__ hin, const float* __restrict__ agg,
    const float* __restrict__ W, const float* __restrict__ bias,
    const float* __restrict__ g, const float* __restrict__ be,
    float* __restrict__ hout, int N)
{
    __shared__ __align__(16) float w[256 * HD];     // 128 KB
    __shared__ __align__(16) float cat[2][256];
    __shared__ float red[2][2][2];
    for (int i = threadIdx.x; i < 256 * HD; i += 256) w[i] = W[i];
    int sub = threadIdx.x >> 7, t = threadIdx.x & 127;
    float bj = bias[t], gj = g[t], bej = be[t];
    __syncthreads();
    for (int base = blockIdx.x * 2; base < N; base += gridDim.x * 2) {
        int i = base + sub; bool val = i < N;
        float hv = 0.f;
        if (val) {
            hv = hin[(size_t)i * HD + t];
            cat[sub][t] = hv;
            cat[sub][128 + t] = agg[(size_t)i * HD + t];
        }
        __syncthreads();
        float acc = bj + hv;   // residual
        const float* xr = cat[sub];
        #pragma unroll 8
        for (int k = 0; k < 256; k += 4) {
            float4 xv = *(const float4*)(xr + k);
            acc = fmaf(xv.x, w[(k + 0) * HD + t], acc);
            acc = fmaf(xv.y, w[(k + 1) * HD + t], acc);
            acc = fmaf(xv.z, w[(k + 2) * HD + t], acc);
            acc = fmaf(xv.w, w[(k + 3) * HD + t], acc);
        }
        float s = wave_sum(acc), s2 = wave_sum(acc * acc);
        int lane = threadIdx.x & 63;
        if (lane == 0) { red[sub][0][t >> 6] = s; red[sub][1][t >> 6] = s2; }
        __syncthreads();
        float mu  = (red[sub][0][0] + red[sub][0][1]) * (1.f / 128.f);
        float var = (red[sub][1][0] + red[sub][1][1]) * (1.f / 128.f) - mu * mu;
        float y = (acc - mu) * rsqrtf(var + LN_EPS) * gj + bej;
        if (val) hout[(size_t)i * HD + t] = fmaxf(y, 0.f);
        __syncthreads();
    }
}

// logits = relu(h@W1+b1)@W2+b2   W1:(128,64) W2:(64,40)
__global__ __launch_bounds__(256) void cls_kernel(
    const float* __restrict__ hin, const float* __restrict__ W1,
    const float* __restrict__ b1, const float* __restrict__ W2,
    const float* __restrict__ b2, float* __restrict__ out, int N)
{
    __shared__ __align__(16) float w1[HD * 64];     // 32 KB
    __shared__ __align__(16) float w2[64 * 40];     // 10 KB
    __shared__ __align__(16) float hs[4][HD];
    __shared__ float ts[4][64];
    for (int i = threadIdx.x; i < HD * 64; i += 256) w1[i] = W1[i];
    for (int i = threadIdx.x; i < 64 * 40; i += 256) w2[i] = W2[i];
    int sub = threadIdx.x >> 6, t = threadIdx.x & 63;
    float b1j = b1[t];
    float b2j = (t < 40) ? b2[t] : 0.f;
    __syncthreads();
    for (int base = blockIdx.x * 4; base < N; base += gridDim.x * 4) {
        int i = base + sub; bool val = i < N;
        if (val) { hs[sub][t] = hin[(size_t)i * HD + t]; hs[sub][64 + t] = hin[(size_t)i * HD + 64 + t]; }
        __syncthreads();
        float acc = b1j;
        const float* hr = hs[sub];
        #pragma unroll 8
        for (int k = 0; k < HD; k += 4) {
            float4 hv = *(const float4*)(hr + k);
            acc = fmaf(hv.x, w1[(k + 0) * 64 + t], acc);
            acc = fmaf(hv.y, w1[(k + 1) * 64 + t], acc);
            acc = fmaf(hv.z, w1[(k + 2) * 64 + t], acc);
            acc = fmaf(hv.w, w1[(k + 3) * 64 + t], acc);
        }
        ts[sub][t] = fmaxf(acc, 0.f);
        __syncthreads();
        if (val && t < 40) {
            float o = b2j;
            const float* tr = ts[sub];
            #pragma unroll 8
            for (int k = 0; k < 64; k++) o = fmaf(tr[k], w2[k * 40 + t], o);
            out[(size_t)i * 40 + t] = o;
        }
        __syncthreads();
    }
}

extern "C" void kernel_launch(void* const* d_in, const int* in_sizes, int n_in,
                              void* d_out, int out_size, void* d_ws, size_t ws_size,
                              hipStream_t stream)
{
    const float* x      = (const float*)d_in[0];
    const int*   ei     = (const int*)d_in[1];
    const float* proj_W = (const float*)d_in[2];
    const float* proj_b = (const float*)d_in[3];
    const float* ln0_g  = (const float*)d_in[4];
    const float* ln0_b  = (const float*)d_in[5];
    const float* sim_W1 = (const float*)d_in[6];
    const float* sim_b1 = (const float*)d_in[7];
    const float* sim_W2 = (const float*)d_in[8];
    const float* sim_b2 = (const float*)d_in[9];
    const float* W_msg  = (const float*)d_in[10];
    const float* W_upd  = (const float*)d_in[11];
    const float* b_upd  = (const float*)d_in[12];
    const float* ln_g   = (const float*)d_in[13];
    const float* ln_b   = (const float*)d_in[14];
    const float* cls_W1 = (const float*)d_in[15];
    const float* cls_b1 = (const float*)d_in[16];
    const float* cls_W2 = (const float*)d_in[17];
    const float* cls_b2 = (const float*)d_in[18];

    int N = in_sizes[0] / 256;
    int E = in_sizes[1] / 2;
    int L = in_sizes[6] / (3 * HD * HD);   // = 3
    const int* srcA = ei;
    const int* dstA = ei + E;

    float* ws = (float*)d_ws;
    size_t nh = (size_t)N * HD;
    float* h   = ws;
    float* A   = h + nh;
    float* B   = A + nh;
    float* M   = B + nh;
    float* agg = M + nh;

    proj_ln_kernel<<<256, 256, 0, stream>>>(x, proj_W, proj_b, ln0_g, ln0_b, h, N);
    for (int l = 0; l < L; l++) {
        const float* W1 = sim_W1 + (size_t)l * 3 * HD * HD;
        nodegemm_kernel<<<256, 256, 0, stream>>>(h, W1,                      sim_b1 + l * HD, A, N);
        nodegemm_kernel<<<256, 256, 0, stream>>>(h, W1 + HD * HD,            nullptr,         B, N);
        nodegemm_kernel<<<256, 256, 0, stream>>>(h, W_msg + (size_t)l * HD * HD, nullptr,     M, N);
        hipMemsetAsync(agg, 0, nh * sizeof(float), stream);
        edge_kernel<<<1024, 256, 0, stream>>>(h, A, B, M, srcA, dstA,
                                              W1 + 2 * HD * HD, sim_W2 + l * HD, sim_b2 + l,
                                              agg, E, N);
        update_ln_kernel<<<256, 256, 0, stream>>>(h, agg, W_upd + (size_t)l * 2 * HD * HD,
                                                  b_upd + l * HD, ln_g + l * HD, ln_b + l * HD, h, N);
    }
    cls_kernel<<<768, 256, 0, stream>>>(h, cls_W1, cls_b1, cls_W2, cls_b2, (float*)d_out, N);
}

// Round 3
// 912.101 us; speedup vs baseline: 3.5914x; 2.7234x over previous
//
#include <hip/hip_runtime.h>
#include <hip/hip_bf16.h>

#define HD 128
#define LN_EPS 1e-5f

typedef __attribute__((ext_vector_type(8))) short short8;
typedef __attribute__((ext_vector_type(4))) float f32x4;

union BfPack { short8 v; unsigned short u[8]; };

__device__ __forceinline__ unsigned short f2bf(float f) {
    union { float f; unsigned u; } v; v.f = f;
    unsigned r = (v.u + 0x7fffu + ((v.u >> 16) & 1u)) >> 16;
    return (unsigned short)r;
}
__device__ __forceinline__ unsigned pk2(float a, float b) {
    return (unsigned)f2bf(a) | ((unsigned)f2bf(b) << 16);
}

__device__ __forceinline__ float wave_sum_all(float v) {
    #pragma unroll
    for (int o = 32; o > 0; o >>= 1) v += __shfl_xor(v, o);
    return v;
}

// ---------------- generic fp32 GEMM: out[N][128] = cat(in0,in1)[N][K] @ W[K][128] (+bias)(+res)
// wave owns 8 rows; W streamed from global (L2-resident); rows staged in LDS for broadcast.
__global__ __launch_bounds__(256) void gemm_rows_kernel(
    const float* __restrict__ in0, int s0, const float* __restrict__ in1, int s1,
    const float* __restrict__ W, const float* __restrict__ bias,
    const float* __restrict__ res, float* __restrict__ out, int N)
{
    __shared__ __align__(16) float rows[4][8][256];
    int tid = threadIdx.x, wv = tid >> 6, lane = tid & 63;
    int rbase = (blockIdx.x * 4 + wv) * 8;
    if (rbase >= N) return;
    int K = in1 ? 256 : 128;
    int r = lane >> 3, seg = lane & 7;
    int row = min(rbase + r, N - 1);
    {
        const float4* p = (const float4*)(in0 + (size_t)row * s0 + seg * 16);
        float4* q = (float4*)&rows[wv][r][seg * 16];
        #pragma unroll
        for (int i = 0; i < 4; i++) q[i] = p[i];
        if (in1) {
            const float4* p1 = (const float4*)(in1 + (size_t)row * s1 + seg * 16);
            float4* q1 = (float4*)&rows[wv][r][128 + seg * 16];
            #pragma unroll
            for (int i = 0; i < 4; i++) q1[i] = p1[i];
        }
    }
    asm volatile("s_waitcnt lgkmcnt(0)" ::: "memory");
    float2 acc[8];
    float2 bv = make_float2(0.f, 0.f);
    if (bias) bv = *(const float2*)(bias + 2 * lane);
    #pragma unroll
    for (int t = 0; t < 8; t++) acc[t] = bv;
    for (int k = 0; k < K; k += 4) {
        float2 w0 = *(const float2*)(W + (size_t)(k + 0) * 128 + 2 * lane);
        float2 w1 = *(const float2*)(W + (size_t)(k + 1) * 128 + 2 * lane);
        float2 w2 = *(const float2*)(W + (size_t)(k + 2) * 128 + 2 * lane);
        float2 w3 = *(const float2*)(W + (size_t)(k + 3) * 128 + 2 * lane);
        #pragma unroll
        for (int t = 0; t < 8; t++) {
            float4 a = *(const float4*)&rows[wv][t][k];
            acc[t].x = fmaf(a.x, w0.x, acc[t].x); acc[t].y = fmaf(a.x, w0.y, acc[t].y);
            acc[t].x = fmaf(a.y, w1.x, acc[t].x); acc[t].y = fmaf(a.y, w1.y, acc[t].y);
            acc[t].x = fmaf(a.z, w2.x, acc[t].x); acc[t].y = fmaf(a.z, w2.y, acc[t].y);
            acc[t].x = fmaf(a.w, w3.x, acc[t].x); acc[t].y = fmaf(a.w, w3.y, acc[t].y);
        }
    }
    #pragma unroll
    for (int t = 0; t < 8; t++) {
        int rw = rbase + t;
        if (rw < N) {
            float2 o = acc[t];
            if (res) {
                float2 rv = *(const float2*)(res + (size_t)rw * 128 + 2 * lane);
                o.x += rv.x; o.y += rv.y;
            }
            *(float2*)(out + (size_t)rw * 128 + 2 * lane) = o;
        }
    }
}

// ---------------- row-wise LN + relu:  out = relu(LN(in)*g + b)
__global__ __launch_bounds__(256) void ln_relu_kernel(
    const float* __restrict__ in, const float* __restrict__ g,
    const float* __restrict__ b, float* __restrict__ out, int N)
{
    int wv = threadIdx.x >> 6, lane = threadIdx.x & 63;
    int row = blockIdx.x * 4 + wv;
    if (row >= N) return;
    float2 v = *(const float2*)(in + (size_t)row * 128 + 2 * lane);
    float s  = wave_sum_all(v.x + v.y);
    float s2 = wave_sum_all(v.x * v.x + v.y * v.y);
    float mu = s * (1.f / 128.f);
    float var = s2 * (1.f / 128.f) - mu * mu;
    float rs = rsqrtf(var + LN_EPS);
    float2 gv = *(const float2*)(g + 2 * lane);
    float2 bv = *(const float2*)(b + 2 * lane);
    float2 y;
    y.x = fmaxf((v.x - mu) * rs * gv.x + bv.x, 0.f);
    y.y = fmaxf((v.y - mu) * rs * gv.y + bv.y, 0.f);
    *(float2*)(out + (size_t)row * 128 + 2 * lane) = y;
}

// ---------------- CSR build ----------------
__global__ __launch_bounds__(256) void hist_kernel(
    const int* __restrict__ dstA, int* __restrict__ cnt, int E, int Etot)
{
    for (int e = blockIdx.x * 256 + threadIdx.x; e < Etot; e += gridDim.x * 256) {
        int di = (e < E) ? dstA[e] : (e - E);
        atomicAdd(&cnt[di], 1);
    }
}

__global__ __launch_bounds__(256) void scan_kernel(
    const int* __restrict__ cnt, int* __restrict__ rowptr, int* __restrict__ cursor,
    int N, int Etot)
{
    __shared__ int ls[256];
    int t = threadIdx.x;
    int chunk = (N + 255) / 256;
    int lo = t * chunk, hi = min(lo + chunk, N);
    int s = 0;
    for (int i = lo; i < hi; i++) s += cnt[i];
    ls[t] = s;
    __syncthreads();
    for (int off = 1; off < 256; off <<= 1) {
        int v = (t >= off) ? ls[t - off] : 0;
        __syncthreads();
        ls[t] += v;
        __syncthreads();
    }
    int run = ls[t] - s;   // exclusive base
    for (int i = lo; i < hi; i++) {
        rowptr[i] = run; cursor[i] = run;
        run += cnt[i];
    }
    if (t == 0) rowptr[N] = Etot;
}

__global__ __launch_bounds__(256) void scatter_kernel(
    const int* __restrict__ srcA, const int* __restrict__ dstA,
    int* __restrict__ cursor, int* __restrict__ eidx, int* __restrict__ esrc,
    int E, int Etot)
{
    for (int e = blockIdx.x * 256 + threadIdx.x; e < Etot; e += gridDim.x * 256) {
        int si = (e < E) ? srcA[e] : (e - E);
        int di = (e < E) ? dstA[e] : (e - E);
        int pos = atomicAdd(&cursor[di], 1);
        eidx[pos] = e;
        esrc[pos] = si;
    }
}

// ---------------- edge scores via MFMA:  sim=[x_i|x_j|d] (bf16), hmid=relu(sim@W1+b1),
// score=sigmoid(hmid@W2+b2).  W1:(384,128) row-major. 64 edges/block-tile, 4 waves x 32 cols.
__global__ __launch_bounds__(256) void edge_mfma_kernel(
    const float* __restrict__ h, const int* __restrict__ srcA, const int* __restrict__ dstA,
    const float* __restrict__ W1, const float* __restrict__ b1,
    const float* __restrict__ W2, const float* __restrict__ b2p,
    float* __restrict__ score, int E, int Etot)
{
    __shared__ __align__(16) short sim[64 * 384];   // 48 KB, XOR-swizzled
    __shared__ float pl[4][64];
    int tid = threadIdx.x, wv = tid >> 6, lane = tid & 63;
    char* simb = (char*)sim;

    // B-fragments of W1 in registers: 12 K-tiles x 2 N-tiles (wave's 32 cols)
    short8 wf[12][2];
    {
        int kb = (lane >> 4) * 8;
        int cb = wv * 32 + (lane & 15);
        #pragma unroll
        for (int q = 0; q < 12; q++)
            #pragma unroll
            for (int n = 0; n < 2; n++) {
                BfPack u;
                #pragma unroll
                for (int j = 0; j < 8; j++)
                    u.u[j] = f2bf(W1[(size_t)(q * 32 + kb + j) * 128 + cb + n * 16]);
                wf[q][n] = u.v;
            }
    }
    float b1x = b1[wv * 32 + (lane & 15)],      b1y = b1[wv * 32 + 16 + (lane & 15)];
    float w2x = W2[wv * 32 + (lane & 15)],      w2y = W2[wv * 32 + 16 + (lane & 15)];
    float b2 = b2p[0];

    int ntiles = (Etot + 63) >> 6;
    for (int tile = blockIdx.x; tile < ntiles; tile += gridDim.x) {
        int ebase = tile << 6;
        // ---- stage 64 edges x 384 bf16 (each thread: 1 edge, 32 h-cols)
        {
            int el = tid >> 2, seg = tid & 3;
            int e = ebase + el; if (e >= Etot) e = Etot - 1;
            int si = (e < E) ? srcA[e] : (e - E);
            int di = (e < E) ? dstA[e] : (e - E);
            const float4* xi = (const float4*)(h + (size_t)di * 128 + seg * 32);
            const float4* xj = (const float4*)(h + (size_t)si * 128 + seg * 32);
            int sw = (el & 7) << 4;
            int base_e = el * 768 + seg * 64;
            #pragma unroll
            for (int i = 0; i < 8; i++) {
                float4 a = xi[i], b = xj[i];
                uint2 pi = make_uint2(pk2(a.x, a.y), pk2(a.z, a.w));
                uint2 pj = make_uint2(pk2(b.x, b.y), pk2(b.z, b.w));
                uint2 pd = make_uint2(pk2(fabsf(a.x - b.x), fabsf(a.y - b.y)),
                                      pk2(fabsf(a.z - b.z), fabsf(a.w - b.w)));
                int cb = base_e + i * 8;
                *(uint2*)(simb + ((cb      ) ^ sw)) = pi;
                *(uint2*)(simb + ((cb + 256) ^ sw)) = pj;
                *(uint2*)(simb + ((cb + 512) ^ sw)) = pd;
            }
        }
        __syncthreads();
        // ---- MFMA: C[64 edges][32 cols] per wave
        f32x4 acc[4][2];
        #pragma unroll
        for (int m = 0; m < 4; m++)
            #pragma unroll
            for (int n = 0; n < 2; n++)
                #pragma unroll
                for (int r = 0; r < 4; r++) acc[m][n][r] = 0.f;
        #pragma unroll
        for (int q = 0; q < 12; q++) {
            short8 af[4];
            #pragma unroll
            for (int m = 0; m < 4; m++) {
                int el = m * 16 + (lane & 15);
                int addr = (el * 768 + q * 64 + (lane >> 4) * 16) ^ ((el & 7) << 4);
                af[m] = *(const short8*)(simb + addr);
            }
            #pragma unroll
            for (int m = 0; m < 4; m++)
                #pragma unroll
                for (int n = 0; n < 2; n++)
                    acc[m][n] = __builtin_amdgcn_mfma_f32_16x16x32_bf16(af[m], wf[q][n], acc[m][n], 0, 0, 0);
        }
        // ---- relu, dot with W2 over wave's 32 cols, reduce across 16-lane group
        #pragma unroll
        for (int m = 0; m < 4; m++) {
            #pragma unroll
            for (int r = 0; r < 4; r++) {
                float v = fmaxf(acc[m][0][r] + b1x, 0.f) * w2x
                        + fmaxf(acc[m][1][r] + b1y, 0.f) * w2y;
                v += __shfl_xor(v, 1); v += __shfl_xor(v, 2);
                v += __shfl_xor(v, 4); v += __shfl_xor(v, 8);
                if ((lane & 15) == 0) pl[wv][m * 16 + (lane >> 4) * 4 + r] = v;
            }
        }
        __syncthreads();
        if (tid < 64) {
            int e = ebase + tid;
            if (e < Etot) {
                float z = pl[0][tid] + pl[1][tid] + pl[2][tid] + pl[3][tid] + b2;
                score[e] = 1.f / (1.f + __expf(-z));
            }
        }
    }
}

// ---------------- agg[n] = sum over incoming CSR edges of score[e]*M[src[e]]
__global__ __launch_bounds__(256) void gather_kernel(
    const int* __restrict__ rowptr, const int* __restrict__ eidx,
    const int* __restrict__ esrc, const float* __restrict__ score,
    const float* __restrict__ M, float* __restrict__ agg, int N)
{
    int wv = threadIdx.x >> 6, lane = threadIdx.x & 63;
    int node = blockIdx.x * 4 + wv;
    if (node >= N) return;
    int p0 = rowptr[node], p1 = rowptr[node + 1];
    float2 acc = make_float2(0.f, 0.f);
    for (int base = p0; base < p1; base += 64) {
        int cnt = min(64, p1 - base);
        int sidx = 0; float sc = 0.f;
        if (lane < cnt) {
            int ei = eidx[base + lane];
            sidx = esrc[base + lane];
            sc = score[ei];
        }
        for (int i = 0; i < cnt; i++) {
            float s = __shfl(sc, i);
            int sr = __shfl(sidx, i);
            float2 mv = *(const float2*)(M + (size_t)sr * 128 + 2 * lane);
            acc.x = fmaf(s, mv.x, acc.x);
            acc.y = fmaf(s, mv.y, acc.y);
        }
    }
    *(float2*)(agg + (size_t)node * 128 + 2 * lane) = acc;
}

// ---------------- classifier (unchanged)
__global__ __launch_bounds__(256) void cls_kernel(
    const float* __restrict__ hin, const float* __restrict__ W1,
    const float* __restrict__ b1, const float* __restrict__ W2,
    const float* __restrict__ b2, float* __restrict__ out, int N)
{
    __shared__ __align__(16) float w1[HD * 64];
    __shared__ __align__(16) float w2[64 * 40];
    __shared__ __align__(16) float hs[4][HD];
    __shared__ float ts[4][64];
    for (int i = threadIdx.x; i < HD * 64; i += 256) w1[i] = W1[i];
    for (int i = threadIdx.x; i < 64 * 40; i += 256) w2[i] = W2[i];
    int sub = threadIdx.x >> 6, t = threadIdx.x & 63;
    float b1j = b1[t];
    float b2j = (t < 40) ? b2[t] : 0.f;
    __syncthreads();
    for (int base = blockIdx.x * 4; base < N; base += gridDim.x * 4) {
        int i = base + sub; bool val = i < N;
        if (val) { hs[sub][t] = hin[(size_t)i * HD + t]; hs[sub][64 + t] = hin[(size_t)i * HD + 64 + t]; }
        __syncthreads();
        float acc = b1j;
        const float* hr = hs[sub];
        #pragma unroll 8
        for (int k = 0; k < HD; k += 4) {
            float4 hv = *(const float4*)(hr + k);
            acc = fmaf(hv.x, w1[(k + 0) * 64 + t], acc);
            acc = fmaf(hv.y, w1[(k + 1) * 64 + t], acc);
            acc = fmaf(hv.z, w1[(k + 2) * 64 + t], acc);
            acc = fmaf(hv.w, w1[(k + 3) * 64 + t], acc);
        }
        ts[sub][t] = fmaxf(acc, 0.f);
        __syncthreads();
        if (val && t < 40) {
            float o = b2j;
            const float* tr = ts[sub];
            #pragma unroll 8
            for (int k = 0; k < 64; k++) o = fmaf(tr[k], w2[k * 40 + t], o);
            out[(size_t)i * 40 + t] = o;
        }
        __syncthreads();
    }
}

extern "C" void kernel_launch(void* const* d_in, const int* in_sizes, int n_in,
                              void* d_out, int out_size, void* d_ws, size_t ws_size,
                              hipStream_t stream)
{
    const float* x      = (const float*)d_in[0];
    const int*   ei     = (const int*)d_in[1];
    const float* proj_W = (const float*)d_in[2];
    const float* proj_b = (const float*)d_in[3];
    const float* ln0_g  = (const float*)d_in[4];
    const float* ln0_b  = (const float*)d_in[5];
    const float* sim_W1 = (const float*)d_in[6];
    const float* sim_b1 = (const float*)d_in[7];
    const float* sim_W2 = (const float*)d_in[8];
    const float* sim_b2 = (const float*)d_in[9];
    const float* W_msg  = (const float*)d_in[10];
    const float* W_upd  = (const float*)d_in[11];
    const float* b_upd  = (const float*)d_in[12];
    const float* ln_g   = (const float*)d_in[13];
    const float* ln_b   = (const float*)d_in[14];
    const float* cls_W1 = (const float*)d_in[15];
    const float* cls_b1 = (const float*)d_in[16];
    const float* cls_W2 = (const float*)d_in[17];
    const float* cls_b2 = (const float*)d_in[18];

    int N = in_sizes[0] / 256;
    int E = in_sizes[1] / 2;
    int L = in_sizes[6] / (3 * HD * HD);
    int Etot = E + N;
    const int* srcA = ei;
    const int* dstA = ei + E;

    float* ws = (float*)d_ws;
    size_t nh = (size_t)N * HD;
    float* h     = ws;
    float* Mt    = h + nh;
    float* agg   = Mt + nh;
    float* tmp   = agg + nh;
    float* score = tmp + nh;
    int*   cnt    = (int*)(score + Etot + 64);
    int*   rowptr = cnt + N;
    int*   cursor = rowptr + N + 1;
    int*   eidx   = cursor + N;
    int*   esrc   = eidx + Etot;

    int gemm_blocks = (N + 31) / 32;
    int row_blocks  = (N + 3) / 4;

    // CSR build (edge_index constant across layers)
    hipMemsetAsync(cnt, 0, (size_t)N * sizeof(int), stream);
    hist_kernel<<<512, 256, 0, stream>>>(dstA, cnt, E, Etot);
    scan_kernel<<<1, 256, 0, stream>>>(cnt, rowptr, cursor, N, Etot);
    scatter_kernel<<<512, 256, 0, stream>>>(srcA, dstA, cursor, eidx, esrc, E, Etot);

    // h = relu(LN(x @ proj_W + b))
    gemm_rows_kernel<<<gemm_blocks, 256, 0, stream>>>(x, 256, x + 128, 256, proj_W, proj_b, nullptr, tmp, N);
    ln_relu_kernel<<<row_blocks, 256, 0, stream>>>(tmp, ln0_g, ln0_b, h, N);

    for (int l = 0; l < L; l++) {
        const float* W1 = sim_W1 + (size_t)l * 3 * HD * HD;
        // M = h @ W_msg
        gemm_rows_kernel<<<gemm_blocks, 256, 0, stream>>>(h, 128, nullptr, 0, W_msg + (size_t)l * HD * HD,
                                                          nullptr, nullptr, Mt, N);
        // edge scores (bf16 MFMA)
        edge_mfma_kernel<<<1024, 256, 0, stream>>>(h, srcA, dstA, W1, sim_b1 + l * HD,
                                                   sim_W2 + l * HD, sim_b2 + l, score, E, Etot);
        // agg = segment_sum(score * M[src])
        gather_kernel<<<row_blocks, 256, 0, stream>>>(rowptr, eidx, esrc, score, Mt, agg, N);
        // h = relu(LN(cat(h,agg)@W_upd + b + h))
        gemm_rows_kernel<<<gemm_blocks, 256, 0, stream>>>(h, 128, agg, 128, W_upd + (size_t)l * 2 * HD * HD,
                                                          b_upd + l * HD, h, tmp, N);
        ln_relu_kernel<<<row_blocks, 256, 0, stream>>>(tmp, ln_g + l * HD, ln_b + l * HD, h, N);
    }
    cls_kernel<<<768, 256, 0, stream>>>(h, cls_W1, cls_b1, cls_W2, cls_b2, (float*)d_out, N);
}

// Round 6
// 681.422 us; speedup vs baseline: 4.8071x; 1.3385x over previous
//
#include <hip/hip_runtime.h>
#include <hip/hip_bf16.h>

#define HD 128
#define LN_EPS 1e-5f

typedef __attribute__((ext_vector_type(8))) short short8;
typedef __attribute__((ext_vector_type(4))) float f32x4;

__device__ __forceinline__ unsigned short f2bf(float f) {
    union { float f; unsigned u; } v; v.f = f;
    unsigned r = (v.u + 0x7fffu + ((v.u >> 16) & 1u)) >> 16;
    return (unsigned short)r;
}
__device__ __forceinline__ unsigned pk2(float a, float b) {
    return (unsigned)f2bf(a) | ((unsigned)f2bf(b) << 16);
}

__device__ __forceinline__ float wave_sum_all(float v) {
    #pragma unroll
    for (int o = 32; o > 0; o >>= 1) v += __shfl_xor(v, o);
    return v;
}

// ---------------- W1 (384x128 f32, row-major) -> bf16 fragment-major
// out[((q*8+ct)*4+ks)*128 + c*8 + j] = bf16(W1[(q*32+ks*8+j)*128 + ct*16+c])
__global__ __launch_bounds__(256) void w1bf_kernel(
    const float* __restrict__ W1, unsigned short* __restrict__ out)
{
    int idx = blockIdx.x * 256 + threadIdx.x;   // 49152 total
    int j  = idx & 7;
    int c  = (idx >> 3) & 15;
    int ks = (idx >> 7) & 3;
    int ct = (idx >> 9) & 7;
    int q  = idx >> 12;
    out[idx] = f2bf(W1[(size_t)(q * 32 + ks * 8 + j) * 128 + ct * 16 + c]);
}

// ---------------- fp32 GEMM: out[N][128] = cat(in0,in1)[N][K] @ W[K][128] (+bias)(+res)
// optional fused LN+relu epilogue (g != nullptr). Wave owns 8 rows.
__global__ __launch_bounds__(256) void gemm_rows_kernel(
    const float* __restrict__ in0, int s0, const float* __restrict__ in1, int s1,
    const float* __restrict__ W, const float* __restrict__ bias,
    const float* __restrict__ res, const float* __restrict__ g,
    const float* __restrict__ bln, float* __restrict__ out, int N)
{
    __shared__ __align__(16) float rows[4][8][256];
    int tid = threadIdx.x, wv = tid >> 6, lane = tid & 63;
    int rbase = (blockIdx.x * 4 + wv) * 8;
    if (rbase >= N) return;
    int K = in1 ? 256 : 128;
    int r = lane >> 3, seg = lane & 7;
    int row = min(rbase + r, N - 1);
    {
        const float4* p = (const float4*)(in0 + (size_t)row * s0 + seg * 16);
        float4* q = (float4*)&rows[wv][r][seg * 16];
        #pragma unroll
        for (int i = 0; i < 4; i++) q[i] = p[i];
        if (in1) {
            const float4* p1 = (const float4*)(in1 + (size_t)row * s1 + seg * 16);
            float4* q1 = (float4*)&rows[wv][r][128 + seg * 16];
            #pragma unroll
            for (int i = 0; i < 4; i++) q1[i] = p1[i];
        }
    }
    asm volatile("s_waitcnt lgkmcnt(0)" ::: "memory");
    float2 acc[8];
    float2 bv = make_float2(0.f, 0.f);
    if (bias) bv = *(const float2*)(bias + 2 * lane);
    #pragma unroll
    for (int t = 0; t < 8; t++) acc[t] = bv;
    for (int k = 0; k < K; k += 4) {
        float2 w0 = *(const float2*)(W + (size_t)(k + 0) * 128 + 2 * lane);
        float2 w1 = *(const float2*)(W + (size_t)(k + 1) * 128 + 2 * lane);
        float2 w2 = *(const float2*)(W + (size_t)(k + 2) * 128 + 2 * lane);
        float2 w3 = *(const float2*)(W + (size_t)(k + 3) * 128 + 2 * lane);
        #pragma unroll
        for (int t = 0; t < 8; t++) {
            float4 a = *(const float4*)&rows[wv][t][k];
            acc[t].x = fmaf(a.x, w0.x, acc[t].x); acc[t].y = fmaf(a.x, w0.y, acc[t].y);
            acc[t].x = fmaf(a.y, w1.x, acc[t].x); acc[t].y = fmaf(a.y, w1.y, acc[t].y);
            acc[t].x = fmaf(a.z, w2.x, acc[t].x); acc[t].y = fmaf(a.z, w2.y, acc[t].y);
            acc[t].x = fmaf(a.w, w3.x, acc[t].x); acc[t].y = fmaf(a.w, w3.y, acc[t].y);
        }
    }
    if (res) {
        #pragma unroll
        for (int t = 0; t < 8; t++) {
            int rw = rbase + t;
            if (rw < N) {
                float2 rv = *(const float2*)(res + (size_t)rw * 128 + 2 * lane);
                acc[t].x += rv.x; acc[t].y += rv.y;
            }
        }
    }
    if (g) {   // fused LN + relu
        float2 gv = *(const float2*)(g + 2 * lane);
        float2 lv = *(const float2*)(bln + 2 * lane);
        #pragma unroll
        for (int t = 0; t < 8; t++) {
            int rw = rbase + t;
            if (rw >= N) break;
            float s  = wave_sum_all(acc[t].x + acc[t].y);
            float s2 = wave_sum_all(acc[t].x * acc[t].x + acc[t].y * acc[t].y);
            float mu = s * (1.f / 128.f);
            float var = s2 * (1.f / 128.f) - mu * mu;
            float rs = rsqrtf(var + LN_EPS);
            float2 y;
            y.x = fmaxf((acc[t].x - mu) * rs * gv.x + lv.x, 0.f);
            y.y = fmaxf((acc[t].y - mu) * rs * gv.y + lv.y, 0.f);
            *(float2*)(out + (size_t)rw * 128 + 2 * lane) = y;
        }
    } else {
        #pragma unroll
        for (int t = 0; t < 8; t++) {
            int rw = rbase + t;
            if (rw < N) *(float2*)(out + (size_t)rw * 128 + 2 * lane) = acc[t];
        }
    }
}

// ---------------- CSR build ----------------
__global__ __launch_bounds__(256) void hist_kernel(
    const int* __restrict__ dstA, int* __restrict__ cnt, int E, int Etot)
{
    for (int e = blockIdx.x * 256 + threadIdx.x; e < Etot; e += gridDim.x * 256) {
        int di = (e < E) ? dstA[e] : (e - E);
        atomicAdd(&cnt[di], 1);
    }
}

__global__ __launch_bounds__(256) void scan_kernel(
    const int* __restrict__ cnt, int* __restrict__ rowptr, int* __restrict__ cursor,
    int N, int Etot)
{
    __shared__ int ls[256];
    int t = threadIdx.x;
    int chunk = (N + 255) / 256;
    int lo = t * chunk, hi = min(lo + chunk, N);
    int s = 0;
    for (int i = lo; i < hi; i++) s += cnt[i];
    ls[t] = s;
    __syncthreads();
    for (int off = 1; off < 256; off <<= 1) {
        int v = (t >= off) ? ls[t - off] : 0;
        __syncthreads();
        ls[t] += v;
        __syncthreads();
    }
    int run = ls[t] - s;
    for (int i = lo; i < hi; i++) {
        rowptr[i] = run; cursor[i] = run;
        run += cnt[i];
    }
    if (t == 0) rowptr[N] = Etot;
}

__global__ __launch_bounds__(256) void scatter_kernel(
    const int* __restrict__ srcA, const int* __restrict__ dstA,
    int* __restrict__ cursor, int* __restrict__ eidx, int* __restrict__ esrc,
    int E, int Etot)
{
    for (int e = blockIdx.x * 256 + threadIdx.x; e < Etot; e += gridDim.x * 256) {
        int si = (e < E) ? srcA[e] : (e - E);
        int di = (e < E) ? dstA[e] : (e - E);
        int pos = atomicAdd(&cursor[di], 1);
        eidx[pos] = e;
        esrc[pos] = si;
    }
}

// ---------------- edge scores via MFMA
// sim=[x_i|x_j|d] per edge (K=384) staged from FP32 h (d computed in fp32, RTNE pack),
// hmid=relu(sim@W1+b1), score=sigmoid(hmid@W2+b2)
// LDS planes: xi at +0, xj at +16384, d at +32768 (plane = 64 rows x 256 B).
__global__ __launch_bounds__(256) void edge_mfma_kernel(
    const float* __restrict__ h,
    const int* __restrict__ srcA, const int* __restrict__ dstA,
    const unsigned short* __restrict__ w1bf, const float* __restrict__ b1,
    const float* __restrict__ W2, const float* __restrict__ b2p,
    float* __restrict__ score, int E, int Etot)
{
    __shared__ __align__(16) short sim[3][64][128];   // 48 KB, 256B row stride, XOR-swizzled
    __shared__ float pl[4][64];
    int tid = threadIdx.x, wv = tid >> 6, lane = tid & 63;
    char* simb = (char*)sim;

    // W1 fragments: 12 K-tiles x 2 col-tiles, vector loads from fragment-major w1bf
    short8 wf[12][2];
    {
        int ks = lane >> 4, c = lane & 15;
        #pragma unroll
        for (int q = 0; q < 12; q++)
            #pragma unroll
            for (int n = 0; n < 2; n++) {
                int ct = wv * 2 + n;
                wf[q][n] = *(const short8*)(w1bf + (size_t)(((q * 8 + ct) * 4 + ks) * 128 + c * 8));
            }
    }
    float b1x = b1[wv * 32 + (lane & 15)],  b1y = b1[wv * 32 + 16 + (lane & 15)];
    float w2x = W2[wv * 32 + (lane & 15)],  w2y = W2[wv * 32 + 16 + (lane & 15)];
    float b2 = b2p[0];

    int ntiles = (Etot + 63) >> 6;
    for (int tile = blockIdx.x; tile < ntiles; tile += gridDim.x) {
        int ebase = tile << 6;
        // ---- stage 64 edges x (xi|xj|d) bf16; thread: 1 edge, 32 cols (fp32 source)
        {
            int el = tid >> 2, seg = tid & 3;
            int e = ebase + el; if (e >= Etot) e = Etot - 1;
            int si = (e < E) ? srcA[e] : (e - E);
            int di = (e < E) ? dstA[e] : (e - E);
            const float4* xi = (const float4*)(h + (size_t)di * 128 + seg * 32);
            const float4* xj = (const float4*)(h + (size_t)si * 128 + seg * 32);
            int rowoff = el * 256, sw = (el & 7) << 4;
            #pragma unroll
            for (int gseg = 0; gseg < 4; gseg++) {   // 8 floats -> 16B bf16 per tensor
                float4 a0 = xi[2 * gseg], a1 = xi[2 * gseg + 1];
                float4 b0 = xj[2 * gseg], b1v = xj[2 * gseg + 1];
                uint4 pa, pb, pd;
                pa.x = pk2(a0.x, a0.y); pa.y = pk2(a0.z, a0.w);
                pa.z = pk2(a1.x, a1.y); pa.w = pk2(a1.z, a1.w);
                pb.x = pk2(b0.x, b0.y); pb.y = pk2(b0.z, b0.w);
                pb.z = pk2(b1v.x, b1v.y); pb.w = pk2(b1v.z, b1v.w);
                pd.x = pk2(fabsf(a0.x - b0.x), fabsf(a0.y - b0.y));
                pd.y = pk2(fabsf(a0.z - b0.z), fabsf(a0.w - b0.w));
                pd.z = pk2(fabsf(a1.x - b1v.x), fabsf(a1.y - b1v.y));
                pd.w = pk2(fabsf(a1.z - b1v.z), fabsf(a1.w - b1v.w));
                int off = rowoff + ((seg * 64 + gseg * 16) ^ sw);
                *(uint4*)(simb + off)         = pa;   // plane 0: x_i
                *(uint4*)(simb + 16384 + off) = pb;   // plane 1: x_j
                *(uint4*)(simb + 32768 + off) = pd;   // plane 2: |x_i - x_j|
            }
        }
        __syncthreads();
        // ---- MFMA: C[64 edges][32 cols] per wave
        f32x4 acc[4][2];
        #pragma unroll
        for (int m = 0; m < 4; m++)
            #pragma unroll
            for (int n = 0; n < 2; n++)
                #pragma unroll
                for (int r = 0; r < 4; r++) acc[m][n][r] = 0.f;
        #pragma unroll
        for (int q = 0; q < 12; q++) {
            int third = q >> 2;
            int kin = ((q & 3) * 64 + (lane >> 4) * 16);
            short8 af[4];
            #pragma unroll
            for (int m = 0; m < 4; m++) {
                int el = m * 16 + (lane & 15);
                int addr = third * 16384 + el * 256 + (kin ^ ((el & 7) << 4));
                af[m] = *(const short8*)(simb + addr);
            }
            #pragma unroll
            for (int m = 0; m < 4; m++)
                #pragma unroll
                for (int n = 0; n < 2; n++)
                    acc[m][n] = __builtin_amdgcn_mfma_f32_16x16x32_bf16(af[m], wf[q][n], acc[m][n], 0, 0, 0);
        }
        // ---- relu + W2 dot + 16-lane reduce
        #pragma unroll
        for (int m = 0; m < 4; m++) {
            #pragma unroll
            for (int r = 0; r < 4; r++) {
                float v = fmaxf(acc[m][0][r] + b1x, 0.f) * w2x
                        + fmaxf(acc[m][1][r] + b1y, 0.f) * w2y;
                v += __shfl_xor(v, 1); v += __shfl_xor(v, 2);
                v += __shfl_xor(v, 4); v += __shfl_xor(v, 8);
                if ((lane & 15) == 0) pl[wv][m * 16 + (lane >> 4) * 4 + r] = v;
            }
        }
        __syncthreads();
        if (tid < 64) {
            int e = ebase + tid;
            if (e < Etot) {
                float z = pl[0][tid] + pl[1][tid] + pl[2][tid] + pl[3][tid] + b2;
                score[e] = 1.f / (1.f + __expf(-z));
            }
        }
        __syncthreads();
    }
}

// ---------------- agg[n] = sum over incoming CSR edges of score[e]*M[src[e]]
__global__ __launch_bounds__(256) void gather_kernel(
    const int* __restrict__ rowptr, const int* __restrict__ eidx,
    const int* __restrict__ esrc, const float* __restrict__ score,
    const float* __restrict__ M, float* __restrict__ agg, int N)
{
    int wv = threadIdx.x >> 6, lane = threadIdx.x & 63;
    int node = blockIdx.x * 4 + wv;
    if (node >= N) return;
    int p0 = rowptr[node], p1 = rowptr[node + 1];
    float2 acc = make_float2(0.f, 0.f);
    for (int base = p0; base < p1; base += 64) {
        int cnt = min(64, p1 - base);
        int sidx = 0; float sc = 0.f;
        if (lane < cnt) {
            int ei = eidx[base + lane];
            sidx = esrc[base + lane];
            sc = score[ei];
        }
        for (int i = 0; i < cnt; i++) {
            float s = __shfl(sc, i);
            int sr = __shfl(sidx, i);
            float2 mv = *(const float2*)(M + (size_t)sr * 128 + 2 * lane);
            acc.x = fmaf(s, mv.x, acc.x);
            acc.y = fmaf(s, mv.y, acc.y);
        }
    }
    *(float2*)(agg + (size_t)node * 128 + 2 * lane) = acc;
}

// ---------------- classifier
__global__ __launch_bounds__(256) void cls_kernel(
    const float* __restrict__ hin, const float* __restrict__ W1,
    const float* __restrict__ b1, const float* __restrict__ W2,
    const float* __restrict__ b2, float* __restrict__ out, int N)
{
    __shared__ __align__(16) float w1[HD * 64];
    __shared__ __align__(16) float w2[64 * 40];
    __shared__ __align__(16) float hs[4][HD];
    __shared__ float ts[4][64];
    for (int i = threadIdx.x; i < HD * 64; i += 256) w1[i] = W1[i];
    for (int i = threadIdx.x; i < 64 * 40; i += 256) w2[i] = W2[i];
    int sub = threadIdx.x >> 6, t = threadIdx.x & 63;
    float b1j = b1[t];
    float b2j = (t < 40) ? b2[t] : 0.f;
    __syncthreads();
    for (int base = blockIdx.x * 4; base < N; base += gridDim.x * 4) {
        int i = base + sub; bool val = i < N;
        if (val) { hs[sub][t] = hin[(size_t)i * HD + t]; hs[sub][64 + t] = hin[(size_t)i * HD + 64 + t]; }
        __syncthreads();
        float acc = b1j;
        const float* hr = hs[sub];
        #pragma unroll 8
        for (int k = 0; k < HD; k += 4) {
            float4 hv = *(const float4*)(hr + k);
            acc = fmaf(hv.x, w1[(k + 0) * 64 + t], acc);
            acc = fmaf(hv.y, w1[(k + 1) * 64 + t], acc);
            acc = fmaf(hv.z, w1[(k + 2) * 64 + t], acc);
            acc = fmaf(hv.w, w1[(k + 3) * 64 + t], acc);
        }
        ts[sub][t] = fmaxf(acc, 0.f);
        __syncthreads();
        if (val && t < 40) {
            float o = b2j;
            const float* tr = ts[sub];
            #pragma unroll 8
            for (int k = 0; k < 64; k++) o = fmaf(tr[k], w2[k * 40 + t], o);
            out[(size_t)i * 40 + t] = o;
        }
        __syncthreads();
    }
}

extern "C" void kernel_launch(void* const* d_in, const int* in_sizes, int n_in,
                              void* d_out, int out_size, void* d_ws, size_t ws_size,
                              hipStream_t stream)
{
    const float* x      = (const float*)d_in[0];
    const int*   ei     = (const int*)d_in[1];
    const float* proj_W = (const float*)d_in[2];
    const float* proj_b = (const float*)d_in[3];
    const float* ln0_g  = (const float*)d_in[4];
    const float* ln0_b  = (const float*)d_in[5];
    const float* sim_W1 = (const float*)d_in[6];
    const float* sim_b1 = (const float*)d_in[7];
    const float* sim_W2 = (const float*)d_in[8];
    const float* sim_b2 = (const float*)d_in[9];
    const float* W_msg  = (const float*)d_in[10];
    const float* W_upd  = (const float*)d_in[11];
    const float* b_upd  = (const float*)d_in[12];
    const float* ln_g   = (const float*)d_in[13];
    const float* ln_b   = (const float*)d_in[14];
    const float* cls_W1 = (const float*)d_in[15];
    const float* cls_b1 = (const float*)d_in[16];
    const float* cls_W2 = (const float*)d_in[17];
    const float* cls_b2 = (const float*)d_in[18];

    int N = in_sizes[0] / 256;
    int E = in_sizes[1] / 2;
    int L = in_sizes[6] / (3 * HD * HD);
    int Etot = E + N;
    const int* srcA = ei;
    const int* dstA = ei + E;

    float* ws = (float*)d_ws;
    size_t nh = (size_t)N * HD;
    float* h     = ws;
    float* Mt    = h + nh;
    float* agg   = Mt + nh;
    float* score = agg + nh;
    unsigned short* w1bf = (unsigned short*)(score + Etot + 64);  // 49152 shorts
    int*   cnt    = (int*)(w1bf + 49152);
    int*   rowptr = cnt + N;
    int*   cursor = rowptr + N + 1;
    int*   eidx   = cursor + N;
    int*   esrc   = eidx + Etot;

    int gemm_blocks = (N + 31) / 32;
    int row_blocks  = (N + 3) / 4;

    // CSR build (edge_index constant across layers)
    hipMemsetAsync(cnt, 0, (size_t)N * sizeof(int), stream);
    hist_kernel<<<512, 256, 0, stream>>>(dstA, cnt, E, Etot);
    scan_kernel<<<1, 256, 0, stream>>>(cnt, rowptr, cursor, N, Etot);
    scatter_kernel<<<512, 256, 0, stream>>>(srcA, dstA, cursor, eidx, esrc, E, Etot);

    // h = relu(LN(x @ proj_W + b))   (LN fused)
    gemm_rows_kernel<<<gemm_blocks, 256, 0, stream>>>(x, 256, x + 128, 256, proj_W, proj_b,
                                                      nullptr, ln0_g, ln0_b, h, N);

    for (int l = 0; l < L; l++) {
        const float* W1 = sim_W1 + (size_t)l * 3 * HD * HD;
        w1bf_kernel<<<192, 256, 0, stream>>>(W1, w1bf);
        // M = h @ W_msg
        gemm_rows_kernel<<<gemm_blocks, 256, 0, stream>>>(h, 128, nullptr, 0,
                                                          W_msg + (size_t)l * HD * HD,
                                                          nullptr, nullptr, nullptr, nullptr, Mt, N);
        // edge scores (bf16 MFMA, fp32-sourced staging)
        edge_mfma_kernel<<<1024, 256, 0, stream>>>(h, srcA, dstA,
                                                   w1bf, sim_b1 + l * HD,
                                                   sim_W2 + l * HD, sim_b2 + l, score, E, Etot);
        // agg = segment_sum(score * M[src])
        gather_kernel<<<row_blocks, 256, 0, stream>>>(rowptr, eidx, esrc, score, Mt, agg, N);
        // h = relu(LN(cat(h,agg)@W_upd + b + h))  (LN fused, in-place per-row)
        gemm_rows_kernel<<<gemm_blocks, 256, 0, stream>>>(h, 128, agg, 128,
                                                          W_upd + (size_t)l * 2 * HD * HD,
                                                          b_upd + l * HD, h,
                                                          ln_g + l * HD, ln_b + l * HD, h, N);
    }
    cls_kernel<<<768, 256, 0, stream>>>(h, cls_W1, cls_b1, cls_W2, cls_b2, (float*)d_out, N);
}

// Round 7
// 640.494 us; speedup vs baseline: 5.1143x; 1.0639x over previous
//
#include <hip/hip_runtime.h>
#include <hip/hip_bf16.h>

#define HD 128
#define LN_EPS 1e-5f

typedef __attribute__((ext_vector_type(8))) short short8;
typedef __attribute__((ext_vector_type(4))) float f32x4;

__device__ __forceinline__ unsigned short f2bf(float f) {
    union { float f; unsigned u; } v; v.f = f;
    unsigned r = (v.u + 0x7fffu + ((v.u >> 16) & 1u)) >> 16;
    return (unsigned short)r;
}

// hardware packed fp32->bf16 (RNE), 1 instr for 2 values
__device__ __forceinline__ unsigned cvtpk(float lo, float hi) {
    unsigned r;
    asm("v_cvt_pk_bf16_f32 %0, %1, %2" : "=v"(r) : "v"(lo), "v"(hi));
    return r;
}
// packed bf16(|lo|, |hi|) via VOP3 abs input modifiers
__device__ __forceinline__ unsigned cvtpk_abs(float lo, float hi) {
    unsigned r;
    asm("v_cvt_pk_bf16_f32 %0, abs(%1), abs(%2)" : "=v"(r) : "v"(lo), "v"(hi));
    return r;
}

__device__ __forceinline__ float wave_sum_all(float v) {
    #pragma unroll
    for (int o = 32; o > 0; o >>= 1) v += __shfl_xor(v, o);
    return v;
}

// ---------------- W1 (L x 384x128 f32, row-major) -> bf16 fragment-major, all layers
// out[l*49152 + ((q*8+ct)*4+ks)*128 + c*8 + j] = bf16(W1[l][(q*32+ks*8+j)*128 + ct*16+c])
__global__ __launch_bounds__(256) void w1bf_kernel(
    const float* __restrict__ W1, unsigned short* __restrict__ out, int total)
{
    int idx = blockIdx.x * 256 + threadIdx.x;
    if (idx >= total) return;
    int lw  = idx / 49152;
    int rem = idx - lw * 49152;
    int j  = rem & 7;
    int c  = (rem >> 3) & 15;
    int ks = (rem >> 7) & 3;
    int ct = (rem >> 9) & 7;
    int q  = rem >> 12;
    out[idx] = f2bf(W1[(size_t)lw * 49152 + (size_t)(q * 32 + ks * 8 + j) * 128 + ct * 16 + c]);
}

// ---------------- fp32 GEMM: out[N][128] = cat(in0,in1)[N][K] @ W[K][128] (+bias)(+res)
// optional fused LN+relu epilogue (g != nullptr). Wave owns 8 rows.
__global__ __launch_bounds__(256) void gemm_rows_kernel(
    const float* __restrict__ in0, int s0, const float* __restrict__ in1, int s1,
    const float* __restrict__ W, const float* __restrict__ bias,
    const float* __restrict__ res, const float* __restrict__ g,
    const float* __restrict__ bln, float* __restrict__ out, int N)
{
    __shared__ __align__(16) float rows[4][8][256];
    int tid = threadIdx.x, wv = tid >> 6, lane = tid & 63;
    int rbase = (blockIdx.x * 4 + wv) * 8;
    if (rbase >= N) return;
    int K = in1 ? 256 : 128;
    int r = lane >> 3, seg = lane & 7;
    int row = min(rbase + r, N - 1);
    {
        const float4* p = (const float4*)(in0 + (size_t)row * s0 + seg * 16);
        float4* q = (float4*)&rows[wv][r][seg * 16];
        #pragma unroll
        for (int i = 0; i < 4; i++) q[i] = p[i];
        if (in1) {
            const float4* p1 = (const float4*)(in1 + (size_t)row * s1 + seg * 16);
            float4* q1 = (float4*)&rows[wv][r][128 + seg * 16];
            #pragma unroll
            for (int i = 0; i < 4; i++) q1[i] = p1[i];
        }
    }
    asm volatile("s_waitcnt lgkmcnt(0)" ::: "memory");
    float2 acc[8];
    float2 bv = make_float2(0.f, 0.f);
    if (bias) bv = *(const float2*)(bias + 2 * lane);
    #pragma unroll
    for (int t = 0; t < 8; t++) acc[t] = bv;
    for (int k = 0; k < K; k += 4) {
        float2 w0 = *(const float2*)(W + (size_t)(k + 0) * 128 + 2 * lane);
        float2 w1 = *(const float2*)(W + (size_t)(k + 1) * 128 + 2 * lane);
        float2 w2 = *(const float2*)(W + (size_t)(k + 2) * 128 + 2 * lane);
        float2 w3 = *(const float2*)(W + (size_t)(k + 3) * 128 + 2 * lane);
        #pragma unroll
        for (int t = 0; t < 8; t++) {
            float4 a = *(const float4*)&rows[wv][t][k];
            acc[t].x = fmaf(a.x, w0.x, acc[t].x); acc[t].y = fmaf(a.x, w0.y, acc[t].y);
            acc[t].x = fmaf(a.y, w1.x, acc[t].x); acc[t].y = fmaf(a.y, w1.y, acc[t].y);
            acc[t].x = fmaf(a.z, w2.x, acc[t].x); acc[t].y = fmaf(a.z, w2.y, acc[t].y);
            acc[t].x = fmaf(a.w, w3.x, acc[t].x); acc[t].y = fmaf(a.w, w3.y, acc[t].y);
        }
    }
    if (res) {
        #pragma unroll
        for (int t = 0; t < 8; t++) {
            int rw = rbase + t;
            if (rw < N) {
                float2 rv = *(const float2*)(res + (size_t)rw * 128 + 2 * lane);
                acc[t].x += rv.x; acc[t].y += rv.y;
            }
        }
    }
    if (g) {   // fused LN + relu
        float2 gv = *(const float2*)(g + 2 * lane);
        float2 lv = *(const float2*)(bln + 2 * lane);
        #pragma unroll
        for (int t = 0; t < 8; t++) {
            int rw = rbase + t;
            if (rw >= N) break;
            float s  = wave_sum_all(acc[t].x + acc[t].y);
            float s2 = wave_sum_all(acc[t].x * acc[t].x + acc[t].y * acc[t].y);
            float mu = s * (1.f / 128.f);
            float var = s2 * (1.f / 128.f) - mu * mu;
            float rs = rsqrtf(var + LN_EPS);
            float2 y;
            y.x = fmaxf((acc[t].x - mu) * rs * gv.x + lv.x, 0.f);
            y.y = fmaxf((acc[t].y - mu) * rs * gv.y + lv.y, 0.f);
            *(float2*)(out + (size_t)rw * 128 + 2 * lane) = y;
        }
    } else {
        #pragma unroll
        for (int t = 0; t < 8; t++) {
            int rw = rbase + t;
            if (rw < N) *(float2*)(out + (size_t)rw * 128 + 2 * lane) = acc[t];
        }
    }
}

// ---------------- CSR build ----------------
__global__ __launch_bounds__(256) void hist_kernel(
    const int* __restrict__ dstA, int* __restrict__ cnt, int E, int Etot)
{
    for (int e = blockIdx.x * 256 + threadIdx.x; e < Etot; e += gridDim.x * 256) {
        int di = (e < E) ? dstA[e] : (e - E);
        atomicAdd(&cnt[di], 1);
    }
}

__global__ __launch_bounds__(256) void scan_kernel(
    const int* __restrict__ cnt, int* __restrict__ rowptr, int* __restrict__ cursor,
    int N, int Etot)
{
    __shared__ int ls[256];
    int t = threadIdx.x;
    int chunk = (N + 255) / 256;
    int lo = t * chunk, hi = min(lo + chunk, N);
    int s = 0;
    for (int i = lo; i < hi; i++) s += cnt[i];
    ls[t] = s;
    __syncthreads();
    for (int off = 1; off < 256; off <<= 1) {
        int v = (t >= off) ? ls[t - off] : 0;
        __syncthreads();
        ls[t] += v;
        __syncthreads();
    }
    int run = ls[t] - s;
    for (int i = lo; i < hi; i++) {
        rowptr[i] = run; cursor[i] = run;
        run += cnt[i];
    }
    if (t == 0) rowptr[N] = Etot;
}

__global__ __launch_bounds__(256) void scatter_kernel(
    const int* __restrict__ srcA, const int* __restrict__ dstA,
    int* __restrict__ cursor, int* __restrict__ eidx, int* __restrict__ esrc,
    int E, int Etot)
{
    for (int e = blockIdx.x * 256 + threadIdx.x; e < Etot; e += gridDim.x * 256) {
        int si = (e < E) ? srcA[e] : (e - E);
        int di = (e < E) ? dstA[e] : (e - E);
        int pos = atomicAdd(&cursor[di], 1);
        eidx[pos] = e;
        esrc[pos] = si;
    }
}

// ---------------- edge scores via MFMA
// sim=[x_i|x_j|d] per edge (K=384) staged from FP32 h (d in fp32, HW cvt_pk RNE),
// hmid=relu(sim@W1+b1), score=sigmoid(hmid@W2+b2)
// LDS planes: xi at +0, xj at +16384, d at +32768 (plane = 64 rows x 256 B).
__global__ __launch_bounds__(256) void edge_mfma_kernel(
    const float* __restrict__ h,
    const int* __restrict__ srcA, const int* __restrict__ dstA,
    const unsigned short* __restrict__ w1bf, const float* __restrict__ b1,
    const float* __restrict__ W2, const float* __restrict__ b2p,
    float* __restrict__ score, int E, int Etot)
{
    __shared__ __align__(16) short sim[3][64][128];   // 48 KB, 256B row stride, XOR-swizzled
    __shared__ float pl[4][64];
    int tid = threadIdx.x, wv = tid >> 6, lane = tid & 63;
    char* simb = (char*)sim;

    // W1 fragments: 12 K-tiles x 2 col-tiles, vector loads from fragment-major w1bf
    short8 wf[12][2];
    {
        int ks = lane >> 4, c = lane & 15;
        #pragma unroll
        for (int q = 0; q < 12; q++)
            #pragma unroll
            for (int n = 0; n < 2; n++) {
                int ct = wv * 2 + n;
                wf[q][n] = *(const short8*)(w1bf + (size_t)(((q * 8 + ct) * 4 + ks) * 128 + c * 8));
            }
    }
    float b1x = b1[wv * 32 + (lane & 15)],  b1y = b1[wv * 32 + 16 + (lane & 15)];
    float w2x = W2[wv * 32 + (lane & 15)],  w2y = W2[wv * 32 + 16 + (lane & 15)];
    float b2 = b2p[0];

    int ntiles = (Etot + 63) >> 6;
    for (int tile = blockIdx.x; tile < ntiles; tile += gridDim.x) {
        int ebase = tile << 6;
        // ---- stage 64 edges x (xi|xj|d) bf16; thread: 1 edge, 32 cols (fp32 source)
        {
            int el = tid >> 2, seg = tid & 3;
            int e = ebase + el; if (e >= Etot) e = Etot - 1;
            int si = (e < E) ? srcA[e] : (e - E);
            int di = (e < E) ? dstA[e] : (e - E);
            const float4* xi = (const float4*)(h + (size_t)di * 128 + seg * 32);
            const float4* xj = (const float4*)(h + (size_t)si * 128 + seg * 32);
            int rowoff = el * 256, sw = (el & 7) << 4;
            #pragma unroll
            for (int gseg = 0; gseg < 4; gseg++) {   // 8 floats -> 16B bf16 per tensor
                float4 a0 = xi[2 * gseg], a1 = xi[2 * gseg + 1];
                float4 b0 = xj[2 * gseg], b1v = xj[2 * gseg + 1];
                uint4 pa, pb, pd;
                pa.x = cvtpk(a0.x, a0.y);  pa.y = cvtpk(a0.z, a0.w);
                pa.z = cvtpk(a1.x, a1.y);  pa.w = cvtpk(a1.z, a1.w);
                pb.x = cvtpk(b0.x, b0.y);  pb.y = cvtpk(b0.z, b0.w);
                pb.z = cvtpk(b1v.x, b1v.y); pb.w = cvtpk(b1v.z, b1v.w);
                pd.x = cvtpk_abs(a0.x - b0.x, a0.y - b0.y);
                pd.y = cvtpk_abs(a0.z - b0.z, a0.w - b0.w);
                pd.z = cvtpk_abs(a1.x - b1v.x, a1.y - b1v.y);
                pd.w = cvtpk_abs(a1.z - b1v.z, a1.w - b1v.w);
                int off = rowoff + ((seg * 64 + gseg * 16) ^ sw);
                *(uint4*)(simb + off)         = pa;   // plane 0: x_i
                *(uint4*)(simb + 16384 + off) = pb;   // plane 1: x_j
                *(uint4*)(simb + 32768 + off) = pd;   // plane 2: |x_i - x_j|
            }
        }
        __syncthreads();
        // ---- MFMA: C[64 edges][32 cols] per wave
        f32x4 acc[4][2];
        #pragma unroll
        for (int m = 0; m < 4; m++)
            #pragma unroll
            for (int n = 0; n < 2; n++)
                #pragma unroll
                for (int r = 0; r < 4; r++) acc[m][n][r] = 0.f;
        #pragma unroll
        for (int q = 0; q < 12; q++) {
            int third = q >> 2;
            int kin = ((q & 3) * 64 + (lane >> 4) * 16);
            short8 af[4];
            #pragma unroll
            for (int m = 0; m < 4; m++) {
                int el = m * 16 + (lane & 15);
                int addr = third * 16384 + el * 256 + (kin ^ ((el & 7) << 4));
                af[m] = *(const short8*)(simb + addr);
            }
            #pragma unroll
            for (int m = 0; m < 4; m++)
                #pragma unroll
                for (int n = 0; n < 2; n++)
                    acc[m][n] = __builtin_amdgcn_mfma_f32_16x16x32_bf16(af[m], wf[q][n], acc[m][n], 0, 0, 0);
        }
        // ---- relu + W2 dot + 16-lane reduce
        #pragma unroll
        for (int m = 0; m < 4; m++) {
            #pragma unroll
            for (int r = 0; r < 4; r++) {
                float v = fmaxf(acc[m][0][r] + b1x, 0.f) * w2x
                        + fmaxf(acc[m][1][r] + b1y, 0.f) * w2y;
                v += __shfl_xor(v, 1); v += __shfl_xor(v, 2);
                v += __shfl_xor(v, 4); v += __shfl_xor(v, 8);
                if ((lane & 15) == 0) pl[wv][m * 16 + (lane >> 4) * 4 + r] = v;
            }
        }
        __syncthreads();
        if (tid < 64) {
            int e = ebase + tid;
            if (e < Etot) {
                float z = pl[0][tid] + pl[1][tid] + pl[2][tid] + pl[3][tid] + b2;
                score[e] = 1.f / (1.f + __expf(-z));
            }
        }
        __syncthreads();
    }
}

// ---------------- agg[n] = sum over incoming CSR edges of score[e]*M[src[e]]
__global__ __launch_bounds__(256) void gather_kernel(
    const int* __restrict__ rowptr, const int* __restrict__ eidx,
    const int* __restrict__ esrc, const float* __restrict__ score,
    const float* __restrict__ M, float* __restrict__ agg, int N)
{
    int wv = threadIdx.x >> 6, lane = threadIdx.x & 63;
    int node = blockIdx.x * 4 + wv;
    if (node >= N) return;
    int p0 = rowptr[node], p1 = rowptr[node + 1];
    float2 acc = make_float2(0.f, 0.f);
    for (int base = p0; base < p1; base += 64) {
        int cnt = min(64, p1 - base);
        int sidx = 0; float sc = 0.f;
        if (lane < cnt) {
            int ei = eidx[base + lane];
            sidx = esrc[base + lane];
            sc = score[ei];
        }
        for (int i = 0; i < cnt; i++) {
            float s = __shfl(sc, i);
            int sr = __shfl(sidx, i);
            float2 mv = *(const float2*)(M + (size_t)sr * 128 + 2 * lane);
            acc.x = fmaf(s, mv.x, acc.x);
            acc.y = fmaf(s, mv.y, acc.y);
        }
    }
    *(float2*)(agg + (size_t)node * 128 + 2 * lane) = acc;
}

// ---------------- classifier
__global__ __launch_bounds__(256) void cls_kernel(
    const float* __restrict__ hin, const float* __restrict__ W1,
    const float* __restrict__ b1, const float* __restrict__ W2,
    const float* __restrict__ b2, float* __restrict__ out, int N)
{
    __shared__ __align__(16) float w1[HD * 64];
    __shared__ __align__(16) float w2[64 * 40];
    __shared__ __align__(16) float hs[4][HD];
    __shared__ float ts[4][64];
    for (int i = threadIdx.x; i < HD * 64; i += 256) w1[i] = W1[i];
    for (int i = threadIdx.x; i < 64 * 40; i += 256) w2[i] = W2[i];
    int sub = threadIdx.x >> 6, t = threadIdx.x & 63;
    float b1j = b1[t];
    float b2j = (t < 40) ? b2[t] : 0.f;
    __syncthreads();
    for (int base = blockIdx.x * 4; base < N; base += gridDim.x * 4) {
        int i = base + sub; bool val = i < N;
        if (val) { hs[sub][t] = hin[(size_t)i * HD + t]; hs[sub][64 + t] = hin[(size_t)i * HD + 64 + t]; }
        __syncthreads();
        float acc = b1j;
        const float* hr = hs[sub];
        #pragma unroll 8
        for (int k = 0; k < HD; k += 4) {
            float4 hv = *(const float4*)(hr + k);
            acc = fmaf(hv.x, w1[(k + 0) * 64 + t], acc);
            acc = fmaf(hv.y, w1[(k + 1) * 64 + t], acc);
            acc = fmaf(hv.z, w1[(k + 2) * 64 + t], acc);
            acc = fmaf(hv.w, w1[(k + 3) * 64 + t], acc);
        }
        ts[sub][t] = fmaxf(acc, 0.f);
        __syncthreads();
        if (val && t < 40) {
            float o = b2j;
            const float* tr = ts[sub];
            #pragma unroll 8
            for (int k = 0; k < 64; k++) o = fmaf(tr[k], w2[k * 40 + t], o);
            out[(size_t)i * 40 + t] = o;
        }
        __syncthreads();
    }
}

extern "C" void kernel_launch(void* const* d_in, const int* in_sizes, int n_in,
                              void* d_out, int out_size, void* d_ws, size_t ws_size,
                              hipStream_t stream)
{
    const float* x      = (const float*)d_in[0];
    const int*   ei     = (const int*)d_in[1];
    const float* proj_W = (const float*)d_in[2];
    const float* proj_b = (const float*)d_in[3];
    const float* ln0_g  = (const float*)d_in[4];
    const float* ln0_b  = (const float*)d_in[5];
    const float* sim_W1 = (const float*)d_in[6];
    const float* sim_b1 = (const float*)d_in[7];
    const float* sim_W2 = (const float*)d_in[8];
    const float* sim_b2 = (const float*)d_in[9];
    const float* W_msg  = (const float*)d_in[10];
    const float* W_upd  = (const float*)d_in[11];
    const float* b_upd  = (const float*)d_in[12];
    const float* ln_g   = (const float*)d_in[13];
    const float* ln_b   = (const float*)d_in[14];
    const float* cls_W1 = (const float*)d_in[15];
    const float* cls_b1 = (const float*)d_in[16];
    const float* cls_W2 = (const float*)d_in[17];
    const float* cls_b2 = (const float*)d_in[18];

    int N = in_sizes[0] / 256;
    int E = in_sizes[1] / 2;
    int L = in_sizes[6] / (3 * HD * HD);
    int Etot = E + N;
    const int* srcA = ei;
    const int* dstA = ei + E;

    float* ws = (float*)d_ws;
    size_t nh = (size_t)N * HD;
    float* h     = ws;
    float* Mt    = h + nh;
    float* agg   = Mt + nh;
    float* score = agg + nh;
    unsigned short* w1bf = (unsigned short*)(score + Etot + 64);  // L*49152 shorts
    int*   cnt    = (int*)(w1bf + (size_t)L * 49152);
    int*   rowptr = cnt + N;
    int*   cursor = rowptr + N + 1;
    int*   eidx   = cursor + N;
    int*   esrc   = eidx + Etot;

    int gemm_blocks = (N + 31) / 32;
    int row_blocks  = (N + 3) / 4;

    // CSR build (edge_index constant across layers)
    hipMemsetAsync(cnt, 0, (size_t)N * sizeof(int), stream);
    hist_kernel<<<512, 256, 0, stream>>>(dstA, cnt, E, Etot);
    scan_kernel<<<1, 256, 0, stream>>>(cnt, rowptr, cursor, N, Etot);
    scatter_kernel<<<512, 256, 0, stream>>>(srcA, dstA, cursor, eidx, esrc, E, Etot);

    // all layers' W1 -> bf16 fragment-major, once
    int w1_total = L * 49152;
    w1bf_kernel<<<(w1_total + 255) / 256, 256, 0, stream>>>(sim_W1, w1bf, w1_total);

    // h = relu(LN(x @ proj_W + b))   (LN fused)
    gemm_rows_kernel<<<gemm_blocks, 256, 0, stream>>>(x, 256, x + 128, 256, proj_W, proj_b,
                                                      nullptr, ln0_g, ln0_b, h, N);

    for (int l = 0; l < L; l++) {
        // M = h @ W_msg
        gemm_rows_kernel<<<gemm_blocks, 256, 0, stream>>>(h, 128, nullptr, 0,
                                                          W_msg + (size_t)l * HD * HD,
                                                          nullptr, nullptr, nullptr, nullptr, Mt, N);
        // edge scores (bf16 MFMA, fp32-sourced staging, HW cvt_pk)
        edge_mfma_kernel<<<1024, 256, 0, stream>>>(h, srcA, dstA,
                                                   w1bf + (size_t)l * 49152, sim_b1 + l * HD,
                                                   sim_W2 + l * HD, sim_b2 + l, score, E, Etot);
        // agg = segment_sum(score * M[src])
        gather_kernel<<<row_blocks, 256, 0, stream>>>(rowptr, eidx, esrc, score, Mt, agg, N);
        // h = relu(LN(cat(h,agg)@W_upd + b + h))  (LN fused, in-place per-row)
        gemm_rows_kernel<<<gemm_blocks, 256, 0, stream>>>(h, 128, agg, 128,
                                                          W_upd + (size_t)l * 2 * HD * HD,
                                                          b_upd + l * HD, h,
                                                          ln_g + l * HD, ln_b + l * HD, h, N);
    }
    cls_kernel<<<768, 256, 0, stream>>>(h, cls_W1, cls_b1, cls_W2, cls_b2, (float*)d_out, N);
}